// Round 6
// baseline (27.026 us; speedup 1.0000x reference)
//
#include <hip/hip_runtime.h>
#include <type_traits>

#define FK_EPS 1e-8f
#define BLK 256
#define NJ 24
#define G 8
#define NG (NJ / G)

__global__ __launch_bounds__(BLK, 2)
void fk_kernel(const float* __restrict__ angles,   // (B, 24)
               const float* __restrict__ Torg,     // (24, 4, 4) row-major
               const float* __restrict__ axes,     // (24, 3)
               float* __restrict__ out,            // (B, 75)
               int B)
{
    __shared__ float stage[BLK * 75];

    const int tid = threadIdx.x;
    const int b = blockIdx.x * BLK + tid;

    const float4* ap = reinterpret_cast<const float4*>(angles + (size_t)b * NJ);
    float* outblk = out + (size_t)blockIdx.x * BLK * 75;

    // Running affine transform T = [R | t] (row 3 implicit [0,0,0,1]).
    float t00 = 1.f, t01 = 0.f, t02 = 0.f;
    float t10 = 0.f, t11 = 1.f, t12 = 0.f;
    float t20 = 0.f, t21 = 0.f, t22 = 1.f;
    float tx = 0.f, ty = 0.f, tz = 0.f;

    float* srow = &stage[tid * 75];
    srow[0] = 0.f; srow[1] = 0.f; srow[2] = 0.f;   // base_pos

    // Coalesced flush of output columns [colbase, colbase+NC) for all rows
    // of this block. NC is compile-time -> div becomes magic-mul.
    auto flush_region = [&](int colbase, auto nc_const) {
        constexpr int NC = decltype(nc_const)::value;
        #pragma unroll 1
        for (int i = tid; i < BLK * NC; i += BLK) {
            const int row = i / NC;
            const int col = i - row * NC;
            const int off = row * 75 + colbase + col;
            outblk[off] = stage[off];
        }
    };

    // Software-pipelined angle loads: group g+1's loads issue before group
    // g's compute (named float4 regs only -- no runtime-indexed array).
    float4 av0 = ap[0], av1 = ap[1];

    #pragma unroll 1
    for (int g = 0; g < NG; ++g) {
        float4 nv0, nv1;
        if (g + 1 < NG) { nv0 = ap[2*g + 2]; nv1 = ap[2*g + 3]; }

        float a[G];
        a[0]=av0.x; a[1]=av0.y; a[2]=av0.z; a[3]=av0.w;
        a[4]=av1.x; a[5]=av1.y; a[6]=av1.z; a[7]=av1.w;

        // --- Phase A: 8 independent Rodrigues builds (chain-free ILP) ---
        float R[G][9];
        #pragma unroll
        for (int u = 0; u < G; ++u) {
            const int j = g * G + u;            // uniform -> scalar loads
            const float ang = a[u];
            const float kx = axes[j*3+0] * ang;
            const float ky = axes[j*3+1] * ang;
            const float kz = axes[j*3+2] * ang;
            const float th2 = kx*kx + ky*ky + kz*kz;
            const float theta = __builtin_amdgcn_sqrtf(th2);
            const float s = __sinf(theta);
            const float c = __cosf(theta);

            float A  = s * __builtin_amdgcn_rcpf(theta + FK_EPS);
            float Bc = (1.f - c) * __builtin_amdgcn_rcpf(theta * theta + FK_EPS);
            {   // small-angle Taylor select (matches reference's jnp.where)
                const float h2 = theta * theta, h4 = h2 * h2;
                const float At = 1.f  - h2 * (1.f/6.f)  + h4 * (1.f/120.f);
                const float Bt = 0.5f - h2 * (1.f/24.f) + h4 * (1.f/720.f);
                const bool small = theta < 1e-3f;
                A  = small ? At : A;
                Bc = small ? Bt : Bc;
            }

            R[u][0] = 1.f + Bc * (kx*kx - th2);
            R[u][1] = Bc * kx*ky - A * kz;
            R[u][2] = Bc * kx*kz + A * ky;
            R[u][3] = Bc * kx*ky + A * kz;
            R[u][4] = 1.f + Bc * (ky*ky - th2);
            R[u][5] = Bc * ky*kz - A * kx;
            R[u][6] = Bc * kx*kz - A * ky;
            R[u][7] = Bc * ky*kz + A * kx;
            R[u][8] = 1.f + Bc * (kz*kz - th2);
        }

        // --- Phase B: pure-FMA serial chain through the 8 joints ---
        #pragma unroll
        for (int u = 0; u < G; ++u) {
            const int j = g * G + u;
            const float o00 = Torg[j*16+0],  o01 = Torg[j*16+1],  o02 = Torg[j*16+2],  ox = Torg[j*16+3];
            const float o10 = Torg[j*16+4],  o11 = Torg[j*16+5],  o12 = Torg[j*16+6],  oy = Torg[j*16+7];
            const float o20 = Torg[j*16+8],  o21 = Torg[j*16+9],  o22 = Torg[j*16+10], oz = Torg[j*16+11];

            const float m00 = t00*o00 + t01*o10 + t02*o20;
            const float m01 = t00*o01 + t01*o11 + t02*o21;
            const float m02 = t00*o02 + t01*o12 + t02*o22;
            const float m10 = t10*o00 + t11*o10 + t12*o20;
            const float m11 = t10*o01 + t11*o11 + t12*o21;
            const float m12 = t10*o02 + t11*o12 + t12*o22;
            const float m20 = t20*o00 + t21*o10 + t22*o20;
            const float m21 = t20*o01 + t21*o11 + t22*o21;
            const float m22 = t20*o02 + t21*o12 + t22*o22;

            const float px = t00*ox + t01*oy + t02*oz + tx;
            const float py = t10*ox + t11*oy + t12*oz + ty;
            const float pz = t20*ox + t21*oy + t22*oz + tz;

            const float r00 = R[u][0], r01 = R[u][1], r02 = R[u][2];
            const float r10 = R[u][3], r11 = R[u][4], r12 = R[u][5];
            const float r20 = R[u][6], r21 = R[u][7], r22 = R[u][8];

            t00 = m00*r00 + m01*r10 + m02*r20;
            t01 = m00*r01 + m01*r11 + m02*r21;
            t02 = m00*r02 + m01*r12 + m02*r22;
            t10 = m10*r00 + m11*r10 + m12*r20;
            t11 = m10*r01 + m11*r11 + m12*r21;
            t12 = m10*r02 + m11*r12 + m12*r22;
            t20 = m20*r00 + m21*r10 + m22*r20;
            t21 = m20*r01 + m21*r11 + m22*r21;
            t22 = m20*r02 + m21*r12 + m22*r22;
            tx = px; ty = py; tz = pz;

            srow[3 + 3*j + 0] = px;
            srow[3 + 3*j + 1] = py;
            srow[3 + 3*j + 2] = pz;
        }

        // --- Chunked flush: overlap this group's HBM writes with the next
        // group's compute. Regions are disjoint -> one barrier per group. ---
        __syncthreads();
        if (g == 0)      flush_region(0,  std::integral_constant<int, 27>{});  // base(3) + joints 0..7
        else if (g == 1) flush_region(27, std::integral_constant<int, 24>{});  // joints 8..15
        else             flush_region(51, std::integral_constant<int, 24>{});  // joints 16..23

        av0 = nv0; av1 = nv1;
    }
}

extern "C" void kernel_launch(void* const* d_in, const int* in_sizes, int n_in,
                              void* d_out, int out_size, void* d_ws, size_t ws_size,
                              hipStream_t stream) {
    const float* angles = (const float*)d_in[0];
    const float* Torg   = (const float*)d_in[1];
    const float* axes   = (const float*)d_in[2];
    float* out = (float*)d_out;

    const int B = in_sizes[0] / NJ;          // 131072
    const int grid = (B + BLK - 1) / BLK;    // 512

    fk_kernel<<<grid, BLK, 0, stream>>>(angles, Torg, axes, out, B);
}

// Round 7
// 22.139 us; speedup vs baseline: 1.2207x; 1.2207x over previous
//
#include <hip/hip_runtime.h>

#define BLK 256
#define NJ 24
#define G 8
#define NG (NJ / G)

__global__ __launch_bounds__(BLK, 2)
void fk_kernel(const float* __restrict__ angles,   // (B, 24)
               const float* __restrict__ Torg,     // (24, 4, 4) row-major
               const float* __restrict__ axes,     // (24, 3)
               float* __restrict__ out,            // (B, 75)
               int B)
{
    __shared__ float stage[BLK * 75];
    __shared__ float sQK[NJ * 8];   // per joint: {qw,qx,qy,qz, otx,oty,otz, ax-packed? pad}
    __shared__ float sAx[NJ * 4];   // axis xyz + pad

    const int tid = threadIdx.x;

    // --- One-time: convert T_org rotations to quaternions (threads 0..23) ---
    if (tid < NJ) {
        const float* o = Torg + tid * 16;
        const float m00=o[0], m01=o[1], m02=o[2];
        const float m10=o[4], m11=o[5], m12=o[6];
        const float m20=o[8], m21=o[9], m22=o[10];
        const float tr = m00 + m11 + m22;
        float qw, qx, qy, qz;
        if (tr > 0.f) {
            const float S = sqrtf(tr + 1.f) * 2.f;
            qw = 0.25f * S;
            qx = (m21 - m12) / S;
            qy = (m02 - m20) / S;
            qz = (m10 - m01) / S;
        } else if (m00 > m11 && m00 > m22) {
            const float S = sqrtf(1.f + m00 - m11 - m22) * 2.f;
            qw = (m21 - m12) / S;
            qx = 0.25f * S;
            qy = (m01 + m10) / S;
            qz = (m02 + m20) / S;
        } else if (m11 > m22) {
            const float S = sqrtf(1.f + m11 - m00 - m22) * 2.f;
            qw = (m02 - m20) / S;
            qx = (m01 + m10) / S;
            qy = 0.25f * S;
            qz = (m12 + m21) / S;
        } else {
            const float S = sqrtf(1.f + m22 - m00 - m11) * 2.f;
            qw = (m10 - m01) / S;
            qx = (m02 + m20) / S;
            qy = (m12 + m21) / S;
            qz = 0.25f * S;
        }
        float* q = &sQK[tid * 8];
        q[0] = qw; q[1] = qx; q[2] = qy; q[3] = qz;
        q[4] = o[3]; q[5] = o[7]; q[6] = o[11]; q[7] = 0.f;   // O_t
        float* ax = &sAx[tid * 4];
        ax[0] = axes[tid*3+0]; ax[1] = axes[tid*3+1]; ax[2] = axes[tid*3+2]; ax[3] = 0.f;
    }
    __syncthreads();

    const int b = blockIdx.x * BLK + tid;
    const float4* ap = reinterpret_cast<const float4*>(angles + (size_t)b * NJ);

    // Running transform as quaternion Q + translation t.
    float Qw = 1.f, Qx = 0.f, Qy = 0.f, Qz = 0.f;
    float tx = 0.f, ty = 0.f, tz = 0.f;

    float* srow = &stage[tid * 75];
    srow[0] = 0.f; srow[1] = 0.f; srow[2] = 0.f;   // base_pos

    // Software-pipelined angle loads (named float4 regs only).
    float4 av0 = ap[0], av1 = ap[1];

    #pragma unroll 1
    for (int g = 0; g < NG; ++g) {
        float4 nv0, nv1;
        if (g + 1 < NG) { nv0 = ap[2*g + 2]; nv1 = ap[2*g + 3]; }

        float a[G];
        a[0]=av0.x; a[1]=av0.y; a[2]=av0.z; a[3]=av0.w;
        a[4]=av1.x; a[5]=av1.y; a[6]=av1.z; a[7]=av1.w;

        // --- Phase A: u_j = qO_j * q_j for 8 joints (independent, ILP) ---
        float U[G][4];     // composed joint quats
        float OT[G][3];    // origin translations
        #pragma unroll
        for (int u = 0; u < G; ++u) {
            const int j = g * G + u;
            const float4 qo = *reinterpret_cast<const float4*>(&sQK[j*8]);      // qw qx qy qz
            const float4 ot = *reinterpret_cast<const float4*>(&sQK[j*8+4]);    // otx oty otz pad
            const float4 ax = *reinterpret_cast<const float4*>(&sAx[j*4]);
            OT[u][0] = ot.x; OT[u][1] = ot.y; OT[u][2] = ot.z;

            const float h = 0.5f * a[u];
            const float s = __sinf(h);
            const float c = __cosf(h);
            const float bx = s * ax.x, by = s * ax.y, bz = s * ax.z;

            // Hamilton product u = qo * (c, bx, by, bz)
            U[u][0] = qo.x*c  - qo.y*bx - qo.z*by - qo.w*bz;
            U[u][1] = qo.x*bx + qo.y*c  + qo.z*bz - qo.w*by;
            U[u][2] = qo.x*by - qo.y*bz + qo.z*c  + qo.w*bx;
            U[u][3] = qo.x*bz + qo.y*by - qo.z*bx + qo.w*c;
        }

        // --- Phase B: serial chain, short dep path ---
        #pragma unroll
        for (int u = 0; u < G; ++u) {
            const int j = g * G + u;
            const float ox = OT[u][0], oy = OT[u][1], oz = OT[u][2];

            // t_child = t + R(Q)*O_t   (v' = v + 2*qv x (qv x v + w v))
            const float cx = Qy*oz - Qz*oy + Qw*ox;
            const float cy = Qz*ox - Qx*oz + Qw*oy;
            const float cz = Qx*oy - Qy*ox + Qw*oz;
            const float dx = Qy*cz - Qz*cy;
            const float dy = Qz*cx - Qx*cz;
            const float dz = Qx*cy - Qy*cx;
            tx = tx + ox + 2.f*dx;
            ty = ty + oy + 2.f*dy;
            tz = tz + oz + 2.f*dz;

            // Q = Q * U[u]   (Hamilton)
            const float uw = U[u][0], ux = U[u][1], uy = U[u][2], uz = U[u][3];
            const float nw = Qw*uw - Qx*ux - Qy*uy - Qz*uz;
            const float nx = Qw*ux + Qx*uw + Qy*uz - Qz*uy;
            const float ny = Qw*uy - Qx*uz + Qy*uw + Qz*ux;
            const float nz = Qw*uz + Qx*uy - Qy*ux + Qz*uw;
            Qw = nw; Qx = nx; Qy = ny; Qz = nz;

            srow[3 + 3*j + 0] = tx;
            srow[3 + 3*j + 1] = ty;
            srow[3 + 3*j + 2] = tz;
        }

        av0 = nv0; av1 = nv1;
    }

    __syncthreads();

    // Coalesced float4 writeout of the whole block's 256x75 stage.
    float4* out4 = reinterpret_cast<float4*>(out + (size_t)blockIdx.x * BLK * 75);
    const float4* st4 = reinterpret_cast<const float4*>(stage);
    #pragma unroll 1
    for (int i = tid; i < BLK * 75 / 4; i += BLK) {
        out4[i] = st4[i];
    }
}

extern "C" void kernel_launch(void* const* d_in, const int* in_sizes, int n_in,
                              void* d_out, int out_size, void* d_ws, size_t ws_size,
                              hipStream_t stream) {
    const float* angles = (const float*)d_in[0];
    const float* Torg   = (const float*)d_in[1];
    const float* axes   = (const float*)d_in[2];
    float* out = (float*)d_out;

    const int B = in_sizes[0] / NJ;          // 131072
    const int grid = (B + BLK - 1) / BLK;    // 512

    fk_kernel<<<grid, BLK, 0, stream>>>(angles, Torg, axes, out, B);
}